// Round 2
// baseline (648.335 us; speedup 1.0000x reference)
//
#include <hip/hip_runtime.h>
#include <hip/hip_bf16.h>
#include <stdint.h>

typedef __bf16 bf16x8 __attribute__((ext_vector_type(8)));
typedef float f32x4 __attribute__((ext_vector_type(4)));

__device__ __forceinline__ ushort f2bf(float f) {
  uint32_t u = __builtin_bit_cast(uint32_t, f);
  u += 0x7FFFu + ((u >> 16) & 1u);   // RNE
  return (ushort)(u >> 16);
}

__device__ __forceinline__ void gload16(const void* g, void* l) {
  auto gp = reinterpret_cast<const __attribute__((address_space(1))) char*>(
      reinterpret_cast<uintptr_t>(g));
  auto lp = reinterpret_cast<__attribute__((address_space(3))) char*>(
      reinterpret_cast<uintptr_t>(l));
  __builtin_amdgcn_global_load_lds(gp, lp, 16, 0, 0);
}

__device__ __forceinline__ f32x4 mfma16(bf16x8 a, bf16x8 b, f32x4 c) {
  return __builtin_amdgcn_mfma_f32_16x16x32_bf16(a, b, c, 0, 0, 0);
}

// ---------------- cast fp32 -> bf16 ----------------
__global__ void cast_kernel(const float* __restrict__ src, ushort* __restrict__ dst) {
  int i = (blockIdx.x * 256 + threadIdx.x) * 4;
  float4 v = *(const float4*)(src + i);
  ushort4 o;
  o.x = f2bf(v.x); o.y = f2bf(v.y); o.z = f2bf(v.z); o.w = f2bf(v.w);
  *(ushort4*)(dst + i) = o;
}

// ---------------- GEMM: C = A[M,1024] * W[N,1024]^T (+bias) ----------------
// MODE 0: QKV projection, N=3072. Scatters Q,K -> [B,H,S,64] bf16 (Q pre-scaled
//         by 0.125), V -> [B,H,64,S] bf16 (transposed for attention).
// MODE 1: out projection, N=1024, fp32 output [M,1024] + bias.
template <int MODE>
__global__ __launch_bounds__(256) void gemm_k(
    const ushort* __restrict__ A, const ushort* __restrict__ W,
    const float* __restrict__ b0, const float* __restrict__ b1,
    const float* __restrict__ b2,
    ushort* __restrict__ qo, ushort* __restrict__ ko, ushort* __restrict__ vo,
    float* __restrict__ fo)
{
  __shared__ ushort As[128 * 64];
  __shared__ ushort Bs[128 * 64];
  const int tid = threadIdx.x;
  const int lane = tid & 63, wv = tid >> 6;
  const int wr = wv >> 1, wc = wv & 1;
  const int l15 = lane & 15, l4 = lane >> 4;
  const int m0 = blockIdx.y * 128, n0 = blockIdx.x * 128;

  f32x4 acc[4][4];
  const f32x4 zero = {0.f, 0.f, 0.f, 0.f};
#pragma unroll
  for (int i = 0; i < 4; ++i)
#pragma unroll
    for (int j = 0; j < 4; ++j) acc[i][j] = zero;

  const int soff = wv * 1024 + lane * 16;                  // staging byte offset
  const int a_base = (wr * 64 + l15) * 128 + l4 * 16;      // LDS frag byte offset
  const int b_base = (wc * 64 + l15) * 128 + l4 * 16;
  const char* Ag = (const char*)(A + (size_t)m0 * 1024);
  const char* Wg = (const char*)(W + (size_t)n0 * 1024);

  for (int kt = 0; kt < 16; ++kt) {
    const int k0b = kt * 128;  // 64 k-elems = 128 bytes
#pragma unroll
    for (int sh = 0; sh < 4; ++sh) {
      int off = soff + sh * 4096;
      int row = off >> 7, colb = off & 127;
      gload16(Ag + (size_t)row * 2048 + k0b + colb, (char*)As + off);
      gload16(Wg + (size_t)row * 2048 + k0b + colb, (char*)Bs + off);
    }
    __syncthreads();
#pragma unroll
    for (int kk = 0; kk < 2; ++kk) {
      bf16x8 af[4], bfr[4];
#pragma unroll
      for (int mt = 0; mt < 4; ++mt)
        af[mt] = *(const bf16x8*)((const char*)As + a_base + mt * 2048 + kk * 64);
#pragma unroll
      for (int nt = 0; nt < 4; ++nt)
        bfr[nt] = *(const bf16x8*)((const char*)Bs + b_base + nt * 2048 + kk * 64);
#pragma unroll
      for (int mt = 0; mt < 4; ++mt)
#pragma unroll
        for (int nt = 0; nt < 4; ++nt)
          acc[mt][nt] = mfma16(af[mt], bfr[nt], acc[mt][nt]);
    }
    __syncthreads();
  }

  if (MODE == 0) {
#pragma unroll
    for (int nt = 0; nt < 4; ++nt) {
      int n = n0 + wc * 64 + nt * 16 + l15;
      int seg = n >> 10, nl = n & 1023;
      int h = nl >> 6, d = nl & 63;
      const float* bptr = (seg == 0) ? b0 : (seg == 1) ? b1 : b2;
      float bias = bptr[nl];
#pragma unroll
      for (int mt = 0; mt < 4; ++mt) {
        int m = m0 + wr * 64 + mt * 16 + l4 * 4;
        int b = m >> 11, s = m & 2047;
        if (seg == 2) {
          ushort4 pk;
          pk.x = f2bf(acc[mt][nt][0] + bias);
          pk.y = f2bf(acc[mt][nt][1] + bias);
          pk.z = f2bf(acc[mt][nt][2] + bias);
          pk.w = f2bf(acc[mt][nt][3] + bias);
          *(ushort4*)(vo + (size_t)((b * 16 + h) * 64 + d) * 2048 + s) = pk;
        } else {
          ushort* dst = (seg == 0) ? qo : ko;
          float sc = (seg == 0) ? 0.125f : 1.0f;  // fold 1/sqrt(64) into Q (exact in bf16)
#pragma unroll
          for (int r = 0; r < 4; ++r)
            dst[(size_t)((b * 16 + h) * 2048 + s + r) * 64 + d] =
                f2bf((acc[mt][nt][r] + bias) * sc);
        }
      }
    }
  } else {
#pragma unroll
    for (int nt = 0; nt < 4; ++nt) {
      int n = n0 + wc * 64 + nt * 16 + l15;
      float bias = b0[n];
#pragma unroll
      for (int mt = 0; mt < 4; ++mt) {
        int m = m0 + wr * 64 + mt * 16 + l4 * 4;
#pragma unroll
        for (int r = 0; r < 4; ++r)
          fo[(size_t)(m + r) * 1024 + n] = acc[mt][nt][r] + bias;
      }
    }
  }
}

// ---------------- flash attention (no K/V LDS staging) ----------------
// Q,K: [B,H,S,64] bf16 (Q pre-scaled by 0.125), V: [B,H,64,S] bf16 (transposed).
// O: [B,S,H*64] bf16. Block: 128 q-rows (4 waves x 32), KV tile 64.
// K/V fragments are read directly from global (L2-resident: 256KB/head, 16
// blocks of the same head share one XCD via the bh-fastest grid mapping).
// Only the P (D-layout -> A-layout) transpose uses LDS, per-wave, XOR-swizzled;
// no __syncthreads() anywhere.
__global__ __launch_bounds__(256, 4) void attn_k(
    const ushort* __restrict__ Q, const ushort* __restrict__ K,
    const ushort* __restrict__ V, ushort* __restrict__ O)
{
  __shared__ ushort Ps[4 * 2048];  // per-wave 32x64 bf16, swizzled
  const int tid = threadIdx.x, lane = tid & 63, w = tid >> 6;
  const int l15 = lane & 15, l4 = lane >> 4;
  const int bh = blockIdx.x;        // fastest -> XCD = bh%8 -> head-local L2
  const int q0 = blockIdx.y * 128;
  const int b = bh >> 4, h = bh & 15;
  const ushort* Qh = Q + (size_t)bh * 131072;
  const ushort* Kh = K + (size_t)bh * 131072;
  const ushort* Vh = V + (size_t)bh * 131072;
  char* psb = (char*)Ps + w * 4096;

  bf16x8 qf[2][2];
#pragma unroll
  for (int mt = 0; mt < 2; ++mt)
#pragma unroll
    for (int kk = 0; kk < 2; ++kk)
      qf[mt][kk] = *(const bf16x8*)(Qh + (size_t)(q0 + w * 32 + mt * 16 + l15) * 64 +
                                    kk * 32 + l4 * 8);

  f32x4 oacc[2][4];
  float mrun[2][4], lrun[2][4];
  const f32x4 zero = {0.f, 0.f, 0.f, 0.f};
#pragma unroll
  for (int mt = 0; mt < 2; ++mt) {
#pragma unroll
    for (int dt = 0; dt < 4; ++dt) oacc[mt][dt] = zero;
#pragma unroll
    for (int r = 0; r < 4; ++r) { mrun[mt][r] = -INFINITY; lrun[mt][r] = 0.f; }
  }

  const int swr = ((l15 & 7) ^ ((l15 >> 3) & 1)) << 4;  // read-side Ps swizzle

  for (int j = 0; j < 32; ++j) {
    const ushort* Kt = Kh + (size_t)j * 4096;   // tile base: row t0, 64 elems/row
    const ushort* Vt = Vh + (size_t)j * 64;     // V^T: col t0

    // K fragments direct from global/L2
    bf16x8 kf[2][4];
#pragma unroll
    for (int kk = 0; kk < 2; ++kk)
#pragma unroll
      for (int nt = 0; nt < 4; ++nt)
        kf[kk][nt] = *(const bf16x8*)(Kt + (size_t)(nt * 16 + l15) * 64 + kk * 32 + l4 * 8);

    f32x4 sacc[2][4];
#pragma unroll
    for (int mt = 0; mt < 2; ++mt)
#pragma unroll
      for (int nt = 0; nt < 4; ++nt) sacc[mt][nt] = zero;
#pragma unroll
    for (int kk = 0; kk < 2; ++kk)
#pragma unroll
      for (int mt = 0; mt < 2; ++mt)
#pragma unroll
        for (int nt = 0; nt < 4; ++nt)
          sacc[mt][nt] = mfma16(qf[mt][kk], kf[kk][nt], sacc[mt][nt]);

    // V fragments issued now; latency hides under the softmax VALU phase
    bf16x8 vf[2][4];
#pragma unroll
    for (int kk = 0; kk < 2; ++kk)
#pragma unroll
      for (int dt = 0; dt < 4; ++dt)
        vf[kk][dt] = *(const bf16x8*)(Vt + (size_t)(dt * 16 + l15) * 2048 + kk * 32 + l4 * 8);

    // online softmax (scores pre-scaled via Q)
#pragma unroll
    for (int mt = 0; mt < 2; ++mt) {
      float mx[4], rs[4];
#pragma unroll
      for (int r = 0; r < 4; ++r)
        mx[r] = fmaxf(fmaxf(sacc[mt][0][r], sacc[mt][1][r]),
                      fmaxf(sacc[mt][2][r], sacc[mt][3][r]));
#pragma unroll
      for (int msk = 1; msk <= 8; msk <<= 1)
#pragma unroll
        for (int r = 0; r < 4; ++r) mx[r] = fmaxf(mx[r], __shfl_xor(mx[r], msk));
#pragma unroll
      for (int r = 0; r < 4; ++r) {
        float mnew = fmaxf(mrun[mt][r], mx[r]);
        float f = __expf(mrun[mt][r] - mnew);
        mrun[mt][r] = mnew;
        lrun[mt][r] *= f;
#pragma unroll
        for (int dt = 0; dt < 4; ++dt) oacc[mt][dt][r] *= f;
        float s = 0.f;
#pragma unroll
        for (int nt = 0; nt < 4; ++nt) {
          float p = __expf(sacc[mt][nt][r] - mnew);
          sacc[mt][nt][r] = p;
          s += p;
        }
        rs[r] = s;
      }
#pragma unroll
      for (int msk = 1; msk <= 8; msk <<= 1)
#pragma unroll
        for (int r = 0; r < 4; ++r) rs[r] += __shfl_xor(rs[r], msk);
#pragma unroll
      for (int r = 0; r < 4; ++r) lrun[mt][r] += rs[r];
      // P (D-layout) -> LDS (XOR-swizzled), re-read below in A-layout
#pragma unroll
      for (int nt = 0; nt < 4; ++nt)
#pragma unroll
        for (int r = 0; r < 4; ++r) {
          int row = mt * 16 + l4 * 4 + r;
          int sw = ((row & 7) ^ ((row >> 3) & 1)) << 4;
          *(ushort*)(psb + row * 128 + ((nt * 32 + l15 * 2) ^ sw)) =
              f2bf(sacc[mt][nt][r]);
        }
    }

    // PV (Ps read conflict-free via swizzle; per-wave, no barrier needed)
#pragma unroll
    for (int kk = 0; kk < 2; ++kk) {
      bf16x8 pf[2];
#pragma unroll
      for (int mt = 0; mt < 2; ++mt)
        pf[mt] = *(const bf16x8*)(psb + (mt * 16 + l15) * 128 + ((kk * 64 + l4 * 16) ^ swr));
#pragma unroll
      for (int mt = 0; mt < 2; ++mt)
#pragma unroll
        for (int dt = 0; dt < 4; ++dt)
          oacc[mt][dt] = mfma16(pf[mt], vf[kk][dt], oacc[mt][dt]);
    }
  }

#pragma unroll
  for (int mt = 0; mt < 2; ++mt) {
    float rinv[4];
#pragma unroll
    for (int r = 0; r < 4; ++r) rinv[r] = 1.0f / lrun[mt][r];
#pragma unroll
    for (int dt = 0; dt < 4; ++dt) {
      int d = dt * 16 + l15;
#pragma unroll
      for (int r = 0; r < 4; ++r) {
        int q = q0 + w * 32 + mt * 16 + l4 * 4 + r;
        O[(size_t)(b * 2048 + q) * 1024 + h * 64 + d] = f2bf(oacc[mt][dt][r] * rinv[r]);
      }
    }
  }
}

extern "C" void kernel_launch(void* const* d_in, const int* in_sizes, int n_in,
                              void* d_out, int out_size, void* d_ws, size_t ws_size,
                              hipStream_t stream)
{
  const float* x  = (const float*)d_in[0];
  const float* Wq = (const float*)d_in[1];
  const float* bq = (const float*)d_in[2];
  const float* Wk = (const float*)d_in[3];
  const float* bk = (const float*)d_in[4];
  const float* Wv = (const float*)d_in[5];
  const float* bv = (const float*)d_in[6];
  const float* Wo = (const float*)d_in[7];
  const float* bo = (const float*)d_in[8];
  float* out = (float*)d_out;
  ushort* ws = (ushort*)d_ws;

  // workspace layout (ushort elements); total 75,497,472 bytes
  ushort* xb   = ws;             // x bf16 [8192,1024]; later reused as attn-out
  ushort* wqkv = ws + 8388608;   // [3072,1024]
  ushort* wo   = ws + 11534336;  // [1024,1024]
  ushort* qb   = ws + 12582912;  // [B,H,S,64]
  ushort* kb   = ws + 20971520;  // [B,H,S,64]
  ushort* vb   = ws + 29360128;  // [B,H,64,S]

  cast_kernel<<<8192, 256, 0, stream>>>(x, xb);
  cast_kernel<<<1024, 256, 0, stream>>>(Wq, wqkv);
  cast_kernel<<<1024, 256, 0, stream>>>(Wk, wqkv + 1048576);
  cast_kernel<<<1024, 256, 0, stream>>>(Wv, wqkv + 2097152);
  cast_kernel<<<1024, 256, 0, stream>>>(Wo, wo);

  gemm_k<0><<<dim3(24, 64), 256, 0, stream>>>(xb, wqkv, bq, bk, bv, qb, kb, vb, nullptr);
  attn_k<<<dim3(64, 16), 256, 0, stream>>>(qb, kb, vb, xb);
  gemm_k<1><<<dim3(8, 64), 256, 0, stream>>>(xb, wo, bo, bo, bo, nullptr, nullptr, nullptr, out);
}

// Round 3
// 222.126 us; speedup vs baseline: 2.9188x; 2.9188x over previous
//
#include <hip/hip_runtime.h>
#include <hip/hip_bf16.h>
#include <stdint.h>

typedef __bf16 bf16x8 __attribute__((ext_vector_type(8)));
typedef float f32x4 __attribute__((ext_vector_type(4)));
typedef float f32x16 __attribute__((ext_vector_type(16)));
typedef uint32_t u32x4 __attribute__((ext_vector_type(4)));

__device__ __forceinline__ ushort f2bf(float f) {
  uint32_t u = __builtin_bit_cast(uint32_t, f);
  u += 0x7FFFu + ((u >> 16) & 1u);   // RNE
  return (ushort)(u >> 16);
}

__device__ __forceinline__ uint32_t cvtpk(float lo, float hi) {
  uint32_t r;
  asm("v_cvt_pk_bf16_f32 %0, %1, %2" : "=v"(r) : "v"(lo), "v"(hi));
  return r;
}

__device__ __forceinline__ void gload16(const void* g, void* l) {
  auto gp = reinterpret_cast<const __attribute__((address_space(1))) char*>(
      reinterpret_cast<uintptr_t>(g));
  auto lp = reinterpret_cast<__attribute__((address_space(3))) char*>(
      reinterpret_cast<uintptr_t>(l));
  __builtin_amdgcn_global_load_lds(gp, lp, 16, 0, 0);
}

__device__ __forceinline__ f32x4 mfma16(bf16x8 a, bf16x8 b, f32x4 c) {
  return __builtin_amdgcn_mfma_f32_16x16x32_bf16(a, b, c, 0, 0, 0);
}
__device__ __forceinline__ f32x16 mfma32(bf16x8 a, bf16x8 b, f32x16 c) {
  return __builtin_amdgcn_mfma_f32_32x32x16_bf16(a, b, c, 0, 0, 0);
}

// ---------------- cast fp32 -> bf16 ----------------
__global__ void cast_kernel(const float* __restrict__ src, ushort* __restrict__ dst) {
  int i = (blockIdx.x * 256 + threadIdx.x) * 4;
  float4 v = *(const float4*)(src + i);
  ushort4 o;
  o.x = f2bf(v.x); o.y = f2bf(v.y); o.z = f2bf(v.z); o.w = f2bf(v.w);
  *(ushort4*)(dst + i) = o;
}

// ---------------- GEMM: C = A[M,1024] * W[N,1024]^T (+bias) ----------------
// MODE 0: QKV projection, N=3072. Scatters Q,K -> [B,H,S,64] bf16 (Q pre-scaled
//         by 0.125*log2e for exp2 softmax), V -> [B,H,64,S] bf16 (transposed).
// MODE 1: out projection, N=1024, fp32 output [M,1024] + bias.
template <int MODE>
__global__ __launch_bounds__(256) void gemm_k(
    const ushort* __restrict__ A, const ushort* __restrict__ W,
    const float* __restrict__ b0, const float* __restrict__ b1,
    const float* __restrict__ b2,
    ushort* __restrict__ qo, ushort* __restrict__ ko, ushort* __restrict__ vo,
    float* __restrict__ fo)
{
  __shared__ ushort As[128 * 64];
  __shared__ ushort Bs[128 * 64];
  const int tid = threadIdx.x;
  const int lane = tid & 63, wv = tid >> 6;
  const int wr = wv >> 1, wc = wv & 1;
  const int l15 = lane & 15, l4 = lane >> 4;
  const int m0 = blockIdx.y * 128, n0 = blockIdx.x * 128;

  f32x4 acc[4][4];
  const f32x4 zero = {0.f, 0.f, 0.f, 0.f};
#pragma unroll
  for (int i = 0; i < 4; ++i)
#pragma unroll
    for (int j = 0; j < 4; ++j) acc[i][j] = zero;

  const int soff = wv * 1024 + lane * 16;                  // staging byte offset
  const int a_base = (wr * 64 + l15) * 128 + l4 * 16;      // LDS frag byte offset
  const int b_base = (wc * 64 + l15) * 128 + l4 * 16;
  const char* Ag = (const char*)(A + (size_t)m0 * 1024);
  const char* Wg = (const char*)(W + (size_t)n0 * 1024);

  for (int kt = 0; kt < 16; ++kt) {
    const int k0b = kt * 128;  // 64 k-elems = 128 bytes
#pragma unroll
    for (int sh = 0; sh < 4; ++sh) {
      int off = soff + sh * 4096;
      int row = off >> 7, colb = off & 127;
      gload16(Ag + (size_t)row * 2048 + k0b + colb, (char*)As + off);
      gload16(Wg + (size_t)row * 2048 + k0b + colb, (char*)Bs + off);
    }
    __syncthreads();
#pragma unroll
    for (int kk = 0; kk < 2; ++kk) {
      bf16x8 af[4], bfr[4];
#pragma unroll
      for (int mt = 0; mt < 4; ++mt)
        af[mt] = *(const bf16x8*)((const char*)As + a_base + mt * 2048 + kk * 64);
#pragma unroll
      for (int nt = 0; nt < 4; ++nt)
        bfr[nt] = *(const bf16x8*)((const char*)Bs + b_base + nt * 2048 + kk * 64);
#pragma unroll
      for (int mt = 0; mt < 4; ++mt)
#pragma unroll
        for (int nt = 0; nt < 4; ++nt)
          acc[mt][nt] = mfma16(af[mt], bfr[nt], acc[mt][nt]);
    }
    __syncthreads();
  }

  if (MODE == 0) {
#pragma unroll
    for (int nt = 0; nt < 4; ++nt) {
      int n = n0 + wc * 64 + nt * 16 + l15;
      int seg = n >> 10, nl = n & 1023;
      int h = nl >> 6, d = nl & 63;
      const float* bptr = (seg == 0) ? b0 : (seg == 1) ? b1 : b2;
      float bias = bptr[nl];
#pragma unroll
      for (int mt = 0; mt < 4; ++mt) {
        int m = m0 + wr * 64 + mt * 16 + l4 * 4;
        int b = m >> 11, s = m & 2047;
        if (seg == 2) {
          ushort4 pk;
          pk.x = f2bf(acc[mt][nt][0] + bias);
          pk.y = f2bf(acc[mt][nt][1] + bias);
          pk.z = f2bf(acc[mt][nt][2] + bias);
          pk.w = f2bf(acc[mt][nt][3] + bias);
          *(ushort4*)(vo + (size_t)((b * 16 + h) * 64 + d) * 2048 + s) = pk;
        } else {
          ushort* dst = (seg == 0) ? qo : ko;
          // Q scale: 1/sqrt(64) * log2(e), for exp2-domain softmax
          float sc = (seg == 0) ? 0.18033688011112042f : 1.0f;
#pragma unroll
          for (int r = 0; r < 4; ++r)
            dst[(size_t)((b * 16 + h) * 2048 + s + r) * 64 + d] =
                f2bf((acc[mt][nt][r] + bias) * sc);
        }
      }
    }
  } else {
#pragma unroll
    for (int nt = 0; nt < 4; ++nt) {
      int n = n0 + wc * 64 + nt * 16 + l15;
      float bias = b0[n];
#pragma unroll
      for (int mt = 0; mt < 4; ++mt) {
        int m = m0 + wr * 64 + mt * 16 + l4 * 4;
#pragma unroll
        for (int r = 0; r < 4; ++r)
          fo[(size_t)(m + r) * 1024 + n] = acc[mt][nt][r] + bias;
      }
    }
  }
}

// ---------------- flash attention, swapped 32x32 MFMA structure ----------------
// Q,K: [B,H,S,64] bf16 (Q pre-scaled by 0.125*log2e), V: [B,H,64,S] bf16 (V^T).
// O: [B,S,H*64] bf16. Block: 4 waves x 32 q-rows = 128 q. KV tile 64.
// QK^T computed swapped: S^T[kv,q] = K·Q^T, so each lane owns all scores of one
// q-row (col=lane&31; kv split across the hi=lane>>5 pair). Softmax is in-lane
// + one shfl_xor(32). P->bf16 via v_cvt_pk + shfl_xor(32) feeds PV's B operand
// in-register (no LDS round-trip). PV: O^T[d,q] = V^T · P^T.
// K/V LDS tiles XOR-swizzled via pre-swizzled global_load_lds source.
__global__ __launch_bounds__(256, 4) void attn_k(
    const ushort* __restrict__ Q, const ushort* __restrict__ K,
    const ushort* __restrict__ V, ushort* __restrict__ O)
{
  __shared__ ushort Ks[64 * 64];
  __shared__ ushort Vs[64 * 64];
  const int tid = threadIdx.x, lane = tid & 63, w = tid >> 6;
  const int l31 = lane & 31, hi = lane >> 5;
  const int bh = blockIdx.x;
  const int b = bh >> 4, h = bh & 15;
  const int q = blockIdx.y * 128 + w * 32 + l31;   // this lane's q row
  const ushort* Qh = Q + (size_t)bh * 131072;
  const ushort* Kh = K + (size_t)bh * 131072;
  const ushort* Vh = V + (size_t)bh * 131072;

  // Q fragments (B operand): lane holds Q[q][c*16 + hi*8 .. +7]
  bf16x8 qf[4];
#pragma unroll
  for (int c = 0; c < 4; ++c)
    qf[c] = *(const bf16x8*)(Qh + (size_t)q * 64 + c * 16 + hi * 8);

  f32x16 oacc[2] = {};
  float mrun = -INFINITY, lrun = 0.f;

  const int sw = (l31 & 7) << 4;        // read-side XOR swizzle for this lane
  const int loff = tid * 16;            // staging LDS offset (shot 0)
  const int srow = loff >> 7, scolb = loff & 127;
  const int scol = scolb ^ ((srow & 7) << 4);

  for (int j = 0; j < 32; ++j) {
    // ---- stage K,V tiles (64x64 bf16 each), source pre-swizzled ----
#pragma unroll
    for (int sh = 0; sh < 2; ++sh) {
      int row = srow + sh * 32;
      int off = loff + sh * 4096;
      int sc = scolb ^ ((row & 7) << 4);
      gload16((const char*)Kh + (size_t)j * 8192 + row * 128 + sc, (char*)Ks + off);
      gload16((const char*)Vh + (size_t)row * 4096 + j * 128 + sc, (char*)Vs + off);
    }
    __syncthreads();

    // ---- QK^T (swapped): sacc[t][.] = S^T[kv-tile t][q=l31] ----
    f32x16 sacc[2] = {};
#pragma unroll
    for (int t = 0; t < 2; ++t)
#pragma unroll
      for (int c = 0; c < 4; ++c) {
        int row = t * 32 + l31;
        bf16x8 kfr = *(const bf16x8*)((const char*)Ks + row * 128 +
                                      ((c * 32 + hi * 16) ^ sw));
        sacc[t] = mfma32(kfr, qf[c], sacc[t]);
      }

    // ---- online softmax, in-lane (scores in log2 domain) ----
    float pm = sacc[0][0];
#pragma unroll
    for (int t = 0; t < 2; ++t)
#pragma unroll
      for (int r = 0; r < 16; ++r) pm = fmaxf(pm, sacc[t][r]);
    pm = fmaxf(pm, __shfl_xor(pm, 32));

    if (!__all(pm - mrun <= 8.0f)) {   // defer-max (T13), THR=8 in log2 units
      float mnew = fmaxf(mrun, pm);
      float f = __builtin_amdgcn_exp2f(mrun - mnew);
      lrun *= f;
#pragma unroll
      for (int dt = 0; dt < 2; ++dt)
#pragma unroll
        for (int r = 0; r < 16; ++r) oacc[dt][r] *= f;
      mrun = mnew;
    }

    float ssum = 0.f;
#pragma unroll
    for (int t = 0; t < 2; ++t)
#pragma unroll
      for (int r = 0; r < 16; ++r) {
        float p = __builtin_amdgcn_exp2f(sacc[t][r] - mrun);
        sacc[t][r] = p;
        ssum += p;
      }
    ssum += __shfl_xor(ssum, 32);
    lrun += ssum;

    // ---- pack P to bf16 pairs: wlo/whi[t][g] covers kv32 = g*8+4*hi+{0..3} ----
    uint32_t wlo[2][4], whi[2][4];
#pragma unroll
    for (int t = 0; t < 2; ++t)
#pragma unroll
      for (int g = 0; g < 4; ++g) {
        wlo[t][g] = cvtpk(sacc[t][g * 4 + 0], sacc[t][g * 4 + 1]);
        whi[t][g] = cvtpk(sacc[t][g * 4 + 2], sacc[t][g * 4 + 3]);
      }

    // ---- build PV B-fragments pb[c] (kv chunk c of 16) via lane-pair swap ----
    bf16x8 pb[4];
#pragma unroll
    for (int c = 0; c < 4; ++c) {
      const int t = c >> 1, gb = (c & 1) * 2;
      uint32_t olo = hi ? wlo[t][gb + 1] : wlo[t][gb];      // own g = gb+hi
      uint32_t ohiw = hi ? whi[t][gb + 1] : whi[t][gb];
      uint32_t slo = hi ? wlo[t][gb] : wlo[t][gb + 1];      // send g = gb+1-hi
      uint32_t shiw = hi ? whi[t][gb] : whi[t][gb + 1];
      uint32_t rlo = __shfl_xor(slo, 32);
      uint32_t rhi = __shfl_xor(shiw, 32);
      u32x4 wv_;
      wv_[0] = hi ? rlo : olo;    // k = hi*8 + {0,1}
      wv_[1] = hi ? rhi : ohiw;   // k = hi*8 + {2,3}
      wv_[2] = hi ? olo : rlo;    // k = hi*8 + {4,5}
      wv_[3] = hi ? ohiw : rhi;   // k = hi*8 + {6,7}
      pb[c] = __builtin_bit_cast(bf16x8, wv_);
    }

    // ---- PV: oacc[dt] += V^T-frag x P-frag ----
#pragma unroll
    for (int dt = 0; dt < 2; ++dt)
#pragma unroll
      for (int c = 0; c < 4; ++c) {
        int row = dt * 32 + l31;
        bf16x8 vfr = *(const bf16x8*)((const char*)Vs + row * 128 +
                                      ((c * 32 + hi * 16) ^ sw));
        oacc[dt] = mfma32(vfr, pb[c], oacc[dt]);
      }
    __syncthreads();
  }

  // ---- epilogue: O[b, q, h*64 + d] = oacc^T / lrun ----
  float linv = 1.0f / lrun;
  ushort* Ob = O + (size_t)(b * 2048 + q) * 1024 + h * 64;
#pragma unroll
  for (int dt = 0; dt < 2; ++dt)
#pragma unroll
    for (int g = 0; g < 4; ++g) {
      ushort4 o4;
      o4.x = f2bf(oacc[dt][g * 4 + 0] * linv);
      o4.y = f2bf(oacc[dt][g * 4 + 1] * linv);
      o4.z = f2bf(oacc[dt][g * 4 + 2] * linv);
      o4.w = f2bf(oacc[dt][g * 4 + 3] * linv);
      *(ushort4*)(Ob + dt * 32 + g * 8 + hi * 4) = o4;
    }
}

extern "C" void kernel_launch(void* const* d_in, const int* in_sizes, int n_in,
                              void* d_out, int out_size, void* d_ws, size_t ws_size,
                              hipStream_t stream)
{
  const float* x  = (const float*)d_in[0];
  const float* Wq = (const float*)d_in[1];
  const float* bq = (const float*)d_in[2];
  const float* Wk = (const float*)d_in[3];
  const float* bk = (const float*)d_in[4];
  const float* Wv = (const float*)d_in[5];
  const float* bv = (const float*)d_in[6];
  const float* Wo = (const float*)d_in[7];
  const float* bo = (const float*)d_in[8];
  float* out = (float*)d_out;
  ushort* ws = (ushort*)d_ws;

  // workspace layout (ushort elements)
  ushort* xb   = ws;             // x bf16 [8192,1024]; later reused as attn-out
  ushort* wqkv = ws + 8388608;   // [3072,1024]
  ushort* wo   = ws + 11534336;  // [1024,1024]
  ushort* qb   = ws + 12582912;  // [B,H,S,64]
  ushort* kb   = ws + 20971520;  // [B,H,S,64]
  ushort* vb   = ws + 29360128;  // [B,H,64,S]

  cast_kernel<<<8192, 256, 0, stream>>>(x, xb);
  cast_kernel<<<1024, 256, 0, stream>>>(Wq, wqkv);
  cast_kernel<<<1024, 256, 0, stream>>>(Wk, wqkv + 1048576);
  cast_kernel<<<1024, 256, 0, stream>>>(Wv, wqkv + 2097152);
  cast_kernel<<<1024, 256, 0, stream>>>(Wo, wo);

  gemm_k<0><<<dim3(24, 64), 256, 0, stream>>>(xb, wqkv, bq, bk, bv, qb, kb, vb, nullptr);
  attn_k<<<dim3(64, 16), 256, 0, stream>>>(qb, kb, vb, xb);
  gemm_k<1><<<dim3(8, 64), 256, 0, stream>>>(xb, wo, bo, bo, bo, nullptr, nullptr, nullptr, out);
}

// Round 4
// 220.875 us; speedup vs baseline: 2.9353x; 1.0057x over previous
//
#include <hip/hip_runtime.h>
#include <hip/hip_bf16.h>
#include <stdint.h>

typedef __bf16 bf16x8 __attribute__((ext_vector_type(8)));
typedef float f32x4 __attribute__((ext_vector_type(4)));
typedef float f32x16 __attribute__((ext_vector_type(16)));
typedef uint32_t u32x4 __attribute__((ext_vector_type(4)));

__device__ __forceinline__ ushort f2bf(float f) {
  uint32_t u = __builtin_bit_cast(uint32_t, f);
  u += 0x7FFFu + ((u >> 16) & 1u);   // RNE
  return (ushort)(u >> 16);
}

__device__ __forceinline__ uint32_t cvtpk(float lo, float hi) {
  uint32_t r;
  asm("v_cvt_pk_bf16_f32 %0, %1, %2" : "=v"(r) : "v"(lo), "v"(hi));
  return r;
}

// swaps x.hi31..0 <-> y.lo: after call x = [x.lo | y.lo_old], y = [x.hi_old | y.hi]
__device__ __forceinline__ void p32swap(uint32_t& x, uint32_t& y) {
  asm("v_permlane32_swap_b32 %0, %1" : "+v"(x), "+v"(y));
}

__device__ __forceinline__ void gload16(const void* g, void* l) {
  auto gp = reinterpret_cast<const __attribute__((address_space(1))) char*>(
      reinterpret_cast<uintptr_t>(g));
  auto lp = reinterpret_cast<__attribute__((address_space(3))) char*>(
      reinterpret_cast<uintptr_t>(l));
  __builtin_amdgcn_global_load_lds(gp, lp, 16, 0, 0);
}

__device__ __forceinline__ f32x4 mfma16(bf16x8 a, bf16x8 b, f32x4 c) {
  return __builtin_amdgcn_mfma_f32_16x16x32_bf16(a, b, c, 0, 0, 0);
}
__device__ __forceinline__ f32x16 mfma32(bf16x8 a, bf16x8 b, f32x16 c) {
  return __builtin_amdgcn_mfma_f32_32x32x16_bf16(a, b, c, 0, 0, 0);
}

// ---------------- cast fp32 -> bf16 ----------------
__global__ void cast_kernel(const float* __restrict__ src, ushort* __restrict__ dst) {
  int i = (blockIdx.x * 256 + threadIdx.x) * 4;
  float4 v = *(const float4*)(src + i);
  ushort4 o;
  o.x = f2bf(v.x); o.y = f2bf(v.y); o.z = f2bf(v.z); o.w = f2bf(v.w);
  *(ushort4*)(dst + i) = o;
}

// ---------------- GEMM: C = A[M,1024] * W[N,1024]^T (+bias) ----------------
template <int MODE>
__global__ __launch_bounds__(256) void gemm_k(
    const ushort* __restrict__ A, const ushort* __restrict__ W,
    const float* __restrict__ b0, const float* __restrict__ b1,
    const float* __restrict__ b2,
    ushort* __restrict__ qo, ushort* __restrict__ ko, ushort* __restrict__ vo,
    float* __restrict__ fo)
{
  __shared__ ushort As[128 * 64];
  __shared__ ushort Bs[128 * 64];
  const int tid = threadIdx.x;
  const int lane = tid & 63, wv = tid >> 6;
  const int wr = wv >> 1, wc = wv & 1;
  const int l15 = lane & 15, l4 = lane >> 4;
  const int m0 = blockIdx.y * 128, n0 = blockIdx.x * 128;

  f32x4 acc[4][4];
  const f32x4 zero = {0.f, 0.f, 0.f, 0.f};
#pragma unroll
  for (int i = 0; i < 4; ++i)
#pragma unroll
    for (int j = 0; j < 4; ++j) acc[i][j] = zero;

  const int soff = wv * 1024 + lane * 16;
  const int a_base = (wr * 64 + l15) * 128 + l4 * 16;
  const int b_base = (wc * 64 + l15) * 128 + l4 * 16;
  const char* Ag = (const char*)(A + (size_t)m0 * 1024);
  const char* Wg = (const char*)(W + (size_t)n0 * 1024);

  for (int kt = 0; kt < 16; ++kt) {
    const int k0b = kt * 128;
#pragma unroll
    for (int sh = 0; sh < 4; ++sh) {
      int off = soff + sh * 4096;
      int row = off >> 7, colb = off & 127;
      gload16(Ag + (size_t)row * 2048 + k0b + colb, (char*)As + off);
      gload16(Wg + (size_t)row * 2048 + k0b + colb, (char*)Bs + off);
    }
    __syncthreads();
#pragma unroll
    for (int kk = 0; kk < 2; ++kk) {
      bf16x8 af[4], bfr[4];
#pragma unroll
      for (int mt = 0; mt < 4; ++mt)
        af[mt] = *(const bf16x8*)((const char*)As + a_base + mt * 2048 + kk * 64);
#pragma unroll
      for (int nt = 0; nt < 4; ++nt)
        bfr[nt] = *(const bf16x8*)((const char*)Bs + b_base + nt * 2048 + kk * 64);
#pragma unroll
      for (int mt = 0; mt < 4; ++mt)
#pragma unroll
        for (int nt = 0; nt < 4; ++nt)
          acc[mt][nt] = mfma16(af[mt], bfr[nt], acc[mt][nt]);
    }
    __syncthreads();
  }

  if (MODE == 0) {
#pragma unroll
    for (int nt = 0; nt < 4; ++nt) {
      int n = n0 + wc * 64 + nt * 16 + l15;
      int seg = n >> 10, nl = n & 1023;
      int h = nl >> 6, d = nl & 63;
      const float* bptr = (seg == 0) ? b0 : (seg == 1) ? b1 : b2;
      float bias = bptr[nl];
#pragma unroll
      for (int mt = 0; mt < 4; ++mt) {
        int m = m0 + wr * 64 + mt * 16 + l4 * 4;
        int b = m >> 11, s = m & 2047;
        if (seg == 2) {
          ushort4 pk;
          pk.x = f2bf(acc[mt][nt][0] + bias);
          pk.y = f2bf(acc[mt][nt][1] + bias);
          pk.z = f2bf(acc[mt][nt][2] + bias);
          pk.w = f2bf(acc[mt][nt][3] + bias);
          *(ushort4*)(vo + (size_t)((b * 16 + h) * 64 + d) * 2048 + s) = pk;
        } else {
          ushort* dst = (seg == 0) ? qo : ko;
          // Q scale: 1/sqrt(64) * log2(e), for exp2-domain softmax
          float sc = (seg == 0) ? 0.18033688011112042f : 1.0f;
#pragma unroll
          for (int r = 0; r < 4; ++r)
            dst[(size_t)((b * 16 + h) * 2048 + s + r) * 64 + d] =
                f2bf((acc[mt][nt][r] + bias) * sc);
        }
      }
    }
  } else {
#pragma unroll
    for (int nt = 0; nt < 4; ++nt) {
      int n = n0 + wc * 64 + nt * 16 + l15;
      float bias = b0[n];
#pragma unroll
      for (int mt = 0; mt < 4; ++mt) {
        int m = m0 + wr * 64 + mt * 16 + l4 * 4;
#pragma unroll
        for (int r = 0; r < 4; ++r)
          fo[(size_t)(m + r) * 1024 + n] = acc[mt][nt][r] + bias;
      }
    }
  }
}

// ---------------- flash attention, swapped 32x32 MFMA, dbuf + MFMA-sum ----------------
// Q,K: [B,H,S,64] bf16 (Q pre-scaled by 0.125*log2e), V: [B,H,64,S] bf16 (V^T).
// O: [B,S,H*64] bf16. Block: 4 waves x 32 q-rows = 128 q. KV tile 64, double-buffered.
__global__ __launch_bounds__(256, 4) void attn_k(
    const ushort* __restrict__ Q, const ushort* __restrict__ K,
    const ushort* __restrict__ V, ushort* __restrict__ O)
{
  __shared__ ushort KVs[2][8192];   // per buf: K[64][64] at 0, V[64][64] at +4096
  const int tid = threadIdx.x, lane = tid & 63;
  const int l31 = lane & 31, hi = lane >> 5;
  const int w = tid >> 6;
  const int bh = blockIdx.x;
  const int b = bh >> 4, h = bh & 15;
  const int q = blockIdx.y * 128 + w * 32 + l31;
  const ushort* Qh = Q + (size_t)bh * 131072;
  const ushort* Kh = K + (size_t)bh * 131072;
  const ushort* Vh = V + (size_t)bh * 131072;

  bf16x8 qf[4];
#pragma unroll
  for (int c = 0; c < 4; ++c)
    qf[c] = *(const bf16x8*)(Qh + (size_t)q * 64 + c * 16 + hi * 8);

  u32x4 onebits;
  onebits[0] = 0x3F803F80u; onebits[1] = 0x3F803F80u;
  onebits[2] = 0x3F803F80u; onebits[3] = 0x3F803F80u;
  const bf16x8 ones = __builtin_bit_cast(bf16x8, onebits);

  f32x16 oacc[2] = {};
  float mrun = -INFINITY, lrun = 0.f;

  const int sw = (l31 & 7) << 4;
  const int loff = tid * 16;
  const int srow = loff >> 7, scolb = loff & 127;

  auto STAGE = [&](int buf, int j) {
    char* base = (char*)KVs[buf];
#pragma unroll
    for (int sh = 0; sh < 2; ++sh) {
      int row = srow + sh * 32;
      int off = loff + sh * 4096;
      int sc = scolb ^ ((row & 7) << 4);
      gload16((const char*)Kh + (size_t)j * 8192 + row * 128 + sc, base + off);
      gload16((const char*)Vh + (size_t)row * 4096 + j * 128 + sc, base + 8192 + off);
    }
  };

  STAGE(0, 0);
  __syncthreads();
  int cur = 0;

  for (int j = 0; j < 32; ++j) {
    if (j < 31) STAGE(cur ^ 1, j + 1);   // prefetch; drains at this tile's end barrier
    const char* Kb = (const char*)KVs[cur];
    const char* Vb = Kb + 8192;

    // ---- QK^T (swapped): sacc[t] = S^T[kv-subtile t][q=l31] ----
    f32x16 sacc[2] = {};
    __builtin_amdgcn_s_setprio(1);
#pragma unroll
    for (int t = 0; t < 2; ++t)
#pragma unroll
      for (int c = 0; c < 4; ++c) {
        bf16x8 kfr = *(const bf16x8*)(Kb + (t * 32 + l31) * 128 +
                                      ((c * 32 + hi * 16) ^ sw));
        sacc[t] = mfma32(kfr, qf[c], sacc[t]);
      }
    __builtin_amdgcn_s_setprio(0);

    // ---- online softmax (log2 domain), in-lane max ----
    float a0 = fmaxf(sacc[0][0], sacc[0][1]);
    float a1 = fmaxf(sacc[0][8], sacc[0][9]);
    float a2 = fmaxf(sacc[1][0], sacc[1][1]);
    float a3 = fmaxf(sacc[1][8], sacc[1][9]);
#pragma unroll
    for (int r = 2; r < 8; ++r) {
      a0 = fmaxf(a0, fmaxf(sacc[0][r], sacc[0][r + 8]));
      a2 = fmaxf(a2, fmaxf(sacc[1][r], sacc[1][r + 8]));
    }
    a1 = fmaxf(a1, a3);
    float pm = fmaxf(fmaxf(a0, a2), a1);
    pm = fmaxf(pm, __shfl_xor(pm, 32));

    if (!__all(pm - mrun <= 8.0f)) {   // defer-max (T13)
      float mnew = fmaxf(mrun, pm);
      float f = __builtin_amdgcn_exp2f(mrun - mnew);
      lrun *= f;
#pragma unroll
      for (int dt = 0; dt < 2; ++dt)
#pragma unroll
        for (int r = 0; r < 16; ++r) oacc[dt][r] *= f;
      mrun = mnew;
    }

#pragma unroll
    for (int t = 0; t < 2; ++t)
#pragma unroll
      for (int r = 0; r < 16; ++r)
        sacc[t][r] = __builtin_amdgcn_exp2f(sacc[t][r] - mrun);

    // ---- pack P to bf16: wlo/whi[t][g] = rows g*8+4*hi+{0,1}/{2,3} ----
    uint32_t wlo[2][4], whi[2][4];
#pragma unroll
    for (int t = 0; t < 2; ++t)
#pragma unroll
      for (int g = 0; g < 4; ++g) {
        wlo[t][g] = cvtpk(sacc[t][g * 4 + 0], sacc[t][g * 4 + 1]);
        whi[t][g] = cvtpk(sacc[t][g * 4 + 2], sacc[t][g * 4 + 3]);
      }

    // ---- build PV B-fragments via permlane32_swap (T12) ----
    bf16x8 pb[4];
#pragma unroll
    for (int c = 0; c < 4; ++c) {
      const int t = c >> 1, gb = (c & 1) * 2;
      uint32_t x0 = wlo[t][gb], y0 = wlo[t][gb + 1];
      p32swap(x0, y0);                 // x0 = word0, y0 = word2
      uint32_t x1 = whi[t][gb], y1 = whi[t][gb + 1];
      p32swap(x1, y1);                 // x1 = word1, y1 = word3
      u32x4 wv_;
      wv_[0] = x0; wv_[1] = x1; wv_[2] = y0; wv_[3] = y1;
      pb[c] = __builtin_bit_cast(bf16x8, wv_);
    }

    // ---- PV + row-sum via ones-MFMA ----
    f32x16 ssacc = {};
    __builtin_amdgcn_s_setprio(1);
#pragma unroll
    for (int dt = 0; dt < 2; ++dt)
#pragma unroll
      for (int c = 0; c < 4; ++c) {
        bf16x8 vfr = *(const bf16x8*)(Vb + (dt * 32 + l31) * 128 +
                                      ((c * 32 + hi * 16) ^ sw));
        oacc[dt] = mfma32(vfr, pb[c], oacc[dt]);
      }
#pragma unroll
    for (int c = 0; c < 4; ++c)
      ssacc = mfma32(ones, pb[c], ssacc);
    __builtin_amdgcn_s_setprio(0);
    lrun += ssacc[0];

    __syncthreads();   // implicit vmcnt(0): prefetch landed; all reads of cur done
    cur ^= 1;
  }

  // ---- epilogue: O[b, q, h*64 + d] = oacc^T / lrun ----
  float linv = 1.0f / lrun;
  ushort* Ob = O + (size_t)(b * 2048 + q) * 1024 + h * 64;
#pragma unroll
  for (int dt = 0; dt < 2; ++dt)
#pragma unroll
    for (int g = 0; g < 4; ++g) {
      ushort4 o4;
      o4.x = f2bf(oacc[dt][g * 4 + 0] * linv);
      o4.y = f2bf(oacc[dt][g * 4 + 1] * linv);
      o4.z = f2bf(oacc[dt][g * 4 + 2] * linv);
      o4.w = f2bf(oacc[dt][g * 4 + 3] * linv);
      *(ushort4*)(Ob + dt * 32 + g * 8 + hi * 4) = o4;
    }
}

extern "C" void kernel_launch(void* const* d_in, const int* in_sizes, int n_in,
                              void* d_out, int out_size, void* d_ws, size_t ws_size,
                              hipStream_t stream)
{
  const float* x  = (const float*)d_in[0];
  const float* Wq = (const float*)d_in[1];
  const float* bq = (const float*)d_in[2];
  const float* Wk = (const float*)d_in[3];
  const float* bk = (const float*)d_in[4];
  const float* Wv = (const float*)d_in[5];
  const float* bv = (const float*)d_in[6];
  const float* Wo = (const float*)d_in[7];
  const float* bo = (const float*)d_in[8];
  float* out = (float*)d_out;
  ushort* ws = (ushort*)d_ws;

  // workspace layout (ushort elements)
  ushort* xb   = ws;             // x bf16 [8192,1024]; later reused as attn-out
  ushort* wqkv = ws + 8388608;   // [3072,1024]
  ushort* wo   = ws + 11534336;  // [1024,1024]
  ushort* qb   = ws + 12582912;  // [B,H,S,64]
  ushort* kb   = ws + 20971520;  // [B,H,S,64]
  ushort* vb   = ws + 29360128;  // [B,H,64,S]

  cast_kernel<<<8192, 256, 0, stream>>>(x, xb);
  cast_kernel<<<1024, 256, 0, stream>>>(Wq, wqkv);
  cast_kernel<<<1024, 256, 0, stream>>>(Wk, wqkv + 1048576);
  cast_kernel<<<1024, 256, 0, stream>>>(Wv, wqkv + 2097152);
  cast_kernel<<<1024, 256, 0, stream>>>(Wo, wo);

  gemm_k<0><<<dim3(24, 64), 256, 0, stream>>>(xb, wqkv, bq, bk, bv, qb, kb, vb, nullptr);
  attn_k<<<dim3(64, 16), 256, 0, stream>>>(qb, kb, vb, xb);
  gemm_k<1><<<dim3(8, 64), 256, 0, stream>>>(xb, wo, bo, bo, bo, nullptr, nullptr, nullptr, out);
}

// Round 5
// 199.024 us; speedup vs baseline: 3.2576x; 1.1098x over previous
//
#include <hip/hip_runtime.h>
#include <hip/hip_bf16.h>
#include <stdint.h>

typedef __bf16 bf16x8 __attribute__((ext_vector_type(8)));
typedef float f32x4 __attribute__((ext_vector_type(4)));
typedef float f32x16 __attribute__((ext_vector_type(16)));
typedef uint32_t u32x4 __attribute__((ext_vector_type(4)));

__device__ __forceinline__ ushort f2bf(float f) {
  uint32_t u = __builtin_bit_cast(uint32_t, f);
  u += 0x7FFFu + ((u >> 16) & 1u);   // RNE
  return (ushort)(u >> 16);
}

__device__ __forceinline__ uint32_t cvtpk(float lo, float hi) {
  uint32_t r;
  asm("v_cvt_pk_bf16_f32 %0, %1, %2" : "=v"(r) : "v"(lo), "v"(hi));
  return r;
}

__device__ __forceinline__ void p32swap(uint32_t& x, uint32_t& y) {
  asm("v_permlane32_swap_b32 %0, %1" : "+v"(x), "+v"(y));
}

__device__ __forceinline__ void gload16(const void* g, void* l) {
  auto gp = reinterpret_cast<const __attribute__((address_space(1))) char*>(
      reinterpret_cast<uintptr_t>(g));
  auto lp = reinterpret_cast<__attribute__((address_space(3))) char*>(
      reinterpret_cast<uintptr_t>(l));
  __builtin_amdgcn_global_load_lds(gp, lp, 16, 0, 0);
}

__device__ __forceinline__ f32x4 mfma16(bf16x8 a, bf16x8 b, f32x4 c) {
  return __builtin_amdgcn_mfma_f32_16x16x32_bf16(a, b, c, 0, 0, 0);
}
__device__ __forceinline__ f32x16 mfma32(bf16x8 a, bf16x8 b, f32x16 c) {
  return __builtin_amdgcn_mfma_f32_32x32x16_bf16(a, b, c, 0, 0, 0);
}

#define LGKM0 do { asm volatile("s_waitcnt lgkmcnt(0)" ::: "memory"); \
                   __builtin_amdgcn_sched_barrier(0); } while (0)
#define VMW(n) do { asm volatile("s_waitcnt vmcnt(" #n ")" ::: "memory"); \
                    __builtin_amdgcn_sched_barrier(0); } while (0)
#define SBAR __builtin_amdgcn_s_barrier()

// ---------------- cast fp32 -> bf16 ----------------
__global__ void cast_kernel(const float* __restrict__ src, ushort* __restrict__ dst) {
  int i = (blockIdx.x * 256 + threadIdx.x) * 4;
  float4 v = *(const float4*)(src + i);
  ushort4 o;
  o.x = f2bf(v.x); o.y = f2bf(v.y); o.z = f2bf(v.z); o.w = f2bf(v.w);
  *(ushort4*)(dst + i) = o;
}

// ---------------- GEMM: C = A[M,1024] * W[N,1024]^T (+bias) ----------------
// 128x256 tile, BK=64, 512 threads (8 waves: 2M x 4N, 64x64 per wave).
// Register-extraction pipeline: per K-tile, extract all frags LDS->regs,
// barrier, stage tile t+2 into the freed buffer, MFMA from regs, counted
// vmcnt(6) (2-deep prefetch, never drains to 0 mid-loop).
// MODE 0: QKV projection, N=3072. Scatters Q,K -> [B,H,S,64] (Q pre-scaled by
//         0.125*log2e), V -> [B,H,64,S] (transposed). MODE 1: fp32 out + bias.
template <int MODE>
__global__ __launch_bounds__(512, 2) void gemm_k(
    const ushort* __restrict__ A, const ushort* __restrict__ W,
    const float* __restrict__ b0, const float* __restrict__ b1,
    const float* __restrict__ b2,
    ushort* __restrict__ qo, ushort* __restrict__ ko, ushort* __restrict__ vo,
    float* __restrict__ fo)
{
  __shared__ ushort As[2][128 * 64];
  __shared__ ushort Bs[2][256 * 64];
  const int tid = threadIdx.x;
  const int lane = tid & 63, wid = tid >> 6;
  const int wr = wid >> 2, wc = wid & 3;       // wave: 2M x 4N
  const int l15 = lane & 15, l4 = lane >> 4;

  // chunked-bijective XCD remap (nwg % 8 == 0): lid ordered bx-major
  const int wg = blockIdx.x, nwg = gridDim.x, qch = nwg >> 3;
  const int lid = (wg & 7) * qch + (wg >> 3);
  const int bx = lid >> 6, by = lid & 63;      // 64 m-tiles always (M=8192)
  const int m0 = by * 128, n0 = bx * 256;

  const char* Ag = (const char*)(A + (size_t)m0 * 1024);
  const char* Wg = (const char*)(W + (size_t)n0 * 1024);

  f32x4 acc[4][4] = {};

  // staging offsets (linear LDS dest, pre-swizzled global source)
  const int soff = tid * 16;
  const int srowA0 = soff >> 7, scolb = soff & 127;

  auto STAGE = [&](int d, int kt) {
    const int k0b = kt * 128;
#pragma unroll
    for (int s = 0; s < 2; ++s) {              // A: 128 rows
      int off = soff + s * 8192;
      int row = off >> 7, cb = off & 127;
      int sc = cb ^ ((row & 7) << 4);
      gload16(Ag + (size_t)row * 2048 + k0b + sc, (char*)As[d] + off);
    }
#pragma unroll
    for (int s = 0; s < 4; ++s) {              // B: 256 rows
      int off = soff + s * 8192;
      int row = off >> 7, cb = off & 127;
      int sc = cb ^ ((row & 7) << 4);
      gload16(Wg + (size_t)row * 2048 + k0b + sc, (char*)Bs[d] + off);
    }
  };

  bf16x8 af[4][2], bfr[4][2];

  auto EXTRACT = [&](int d) {
#pragma unroll
    for (int mt = 0; mt < 4; ++mt) {
      int row = wr * 64 + mt * 16 + l15;
      int sw = (row & 7) << 4;
#pragma unroll
      for (int kk = 0; kk < 2; ++kk)
        af[mt][kk] = *(const bf16x8*)((const char*)As[d] + row * 128 +
                                      ((kk * 64 + l4 * 16) ^ sw));
    }
#pragma unroll
    for (int nt = 0; nt < 4; ++nt) {
      int row = wc * 64 + nt * 16 + l15;
      int sw = (row & 7) << 4;
#pragma unroll
      for (int kk = 0; kk < 2; ++kk)
        bfr[nt][kk] = *(const bf16x8*)((const char*)Bs[d] + row * 128 +
                                       ((kk * 64 + l4 * 16) ^ sw));
    }
  };

  auto MFMAS = [&]() {
    __builtin_amdgcn_s_setprio(1);
#pragma unroll
    for (int kk = 0; kk < 2; ++kk)
#pragma unroll
      for (int mt = 0; mt < 4; ++mt)
#pragma unroll
        for (int nt = 0; nt < 4; ++nt)
          acc[mt][nt] = mfma16(af[mt][kk], bfr[nt][kk], acc[mt][nt]);
    __builtin_amdgcn_s_setprio(0);
  };

  // prologue: stage tiles 0,1; wait tile 0 (counted: 6 of tile1 in flight)
  STAGE(0, 0);
  STAGE(1, 1);
  VMW(6); SBAR;

#pragma unroll 2
  for (int t = 0; t < 14; ++t) {
    const int d = t & 1;
    EXTRACT(d);
    LGKM0;            // my reads done (cross-wave: everyone's, after barrier)
    SBAR;             // buf d fully extracted by all waves -> safe to overwrite
    STAGE(d, t + 2);
    MFMAS();
    VMW(6); SBAR;     // tile t+1's 6 loads landed (mine); barrier joins waves
  }
  // t = 14 (no stage; must fully drain tile 15's loads)
  EXTRACT(0); LGKM0; SBAR; MFMAS(); VMW(0); SBAR;
  // t = 15
  EXTRACT(1); LGKM0; MFMAS();

  // ---------------- epilogue ----------------
  if (MODE == 0) {
    const int seg = n0 >> 10;                  // block entirely in one segment
    const int nb = n0 & 1023;
    const float* bptr = (seg == 0) ? b0 : (seg == 1) ? b1 : b2;
#pragma unroll
    for (int nt = 0; nt < 4; ++nt) {
      int nl = nb + wc * 64 + nt * 16 + l15;
      int h = nl >> 6, dd = nl & 63;
      float bias = bptr[nl];
#pragma unroll
      for (int mt = 0; mt < 4; ++mt) {
        int m = m0 + wr * 64 + mt * 16 + l4 * 4;
        int b = m >> 11, s = m & 2047;
        if (seg == 2) {
          ushort4 pk;
          pk.x = f2bf(acc[mt][nt][0] + bias);
          pk.y = f2bf(acc[mt][nt][1] + bias);
          pk.z = f2bf(acc[mt][nt][2] + bias);
          pk.w = f2bf(acc[mt][nt][3] + bias);
          *(ushort4*)(vo + (size_t)((b * 16 + h) * 64 + dd) * 2048 + s) = pk;
        } else {
          ushort* dst = (seg == 0) ? qo : ko;
          // Q scale: 1/sqrt(64) * log2(e) for exp2-domain softmax
          float sc = (seg == 0) ? 0.18033688011112042f : 1.0f;
#pragma unroll
          for (int r = 0; r < 4; ++r)
            dst[(size_t)((b * 16 + h) * 2048 + s + r) * 64 + dd] =
                f2bf((acc[mt][nt][r] + bias) * sc);
        }
      }
    }
  } else {
#pragma unroll
    for (int nt = 0; nt < 4; ++nt) {
      int n = n0 + wc * 64 + nt * 16 + l15;
      float bias = b0[n];
#pragma unroll
      for (int mt = 0; mt < 4; ++mt) {
        int m = m0 + wr * 64 + mt * 16 + l4 * 4;
#pragma unroll
        for (int r = 0; r < 4; ++r)
          fo[(size_t)(m + r) * 1024 + n] = acc[mt][nt][r] + bias;
      }
    }
  }
}

// ---------------- flash attention, swapped 32x32 MFMA, dbuf + MFMA-sum ----------------
// Q,K: [B,H,S,64] bf16 (Q pre-scaled by 0.125*log2e), V: [B,H,64,S] bf16 (V^T).
// O: [B,S,H*64] bf16. Block: 4 waves x 32 q-rows = 128 q. KV tile 64, double-buffered.
__global__ __launch_bounds__(256, 4) void attn_k(
    const ushort* __restrict__ Q, const ushort* __restrict__ K,
    const ushort* __restrict__ V, ushort* __restrict__ O)
{
  __shared__ ushort KVs[2][8192];   // per buf: K[64][64] at 0, V[64][64] at +4096
  const int tid = threadIdx.x, lane = tid & 63;
  const int l31 = lane & 31, hi = lane >> 5;
  const int w = tid >> 6;
  const int bh = blockIdx.x;
  const int b = bh >> 4, h = bh & 15;
  const int q = blockIdx.y * 128 + w * 32 + l31;
  const ushort* Qh = Q + (size_t)bh * 131072;
  const ushort* Kh = K + (size_t)bh * 131072;
  const ushort* Vh = V + (size_t)bh * 131072;

  bf16x8 qf[4];
#pragma unroll
  for (int c = 0; c < 4; ++c)
    qf[c] = *(const bf16x8*)(Qh + (size_t)q * 64 + c * 16 + hi * 8);

  u32x4 onebits;
  onebits[0] = 0x3F803F80u; onebits[1] = 0x3F803F80u;
  onebits[2] = 0x3F803F80u; onebits[3] = 0x3F803F80u;
  const bf16x8 ones = __builtin_bit_cast(bf16x8, onebits);

  f32x16 oacc[2] = {};
  float mrun = -INFINITY, lrun = 0.f;

  const int sw = (l31 & 7) << 4;
  const int loff = tid * 16;
  const int srow = loff >> 7, scolb = loff & 127;

  auto STAGE = [&](int buf, int j) {
    char* base = (char*)KVs[buf];
#pragma unroll
    for (int sh = 0; sh < 2; ++sh) {
      int row = srow + sh * 32;
      int off = loff + sh * 4096;
      int sc = scolb ^ ((row & 7) << 4);
      gload16((const char*)Kh + (size_t)j * 8192 + row * 128 + sc, base + off);
      gload16((const char*)Vh + (size_t)row * 4096 + j * 128 + sc, base + 8192 + off);
    }
  };

  STAGE(0, 0);
  __syncthreads();
  int cur = 0;

  for (int j = 0; j < 32; ++j) {
    if (j < 31) STAGE(cur ^ 1, j + 1);   // prefetch; drains at this tile's end barrier
    const char* Kb = (const char*)KVs[cur];
    const char* Vb = Kb + 8192;

    // ---- QK^T (swapped): sacc[t] = S^T[kv-subtile t][q=l31] ----
    f32x16 sacc[2] = {};
    __builtin_amdgcn_s_setprio(1);
#pragma unroll
    for (int t = 0; t < 2; ++t)
#pragma unroll
      for (int c = 0; c < 4; ++c) {
        bf16x8 kfr = *(const bf16x8*)(Kb + (t * 32 + l31) * 128 +
                                      ((c * 32 + hi * 16) ^ sw));
        sacc[t] = mfma32(kfr, qf[c], sacc[t]);
      }
    __builtin_amdgcn_s_setprio(0);

    // ---- online softmax (log2 domain), in-lane max ----
    float a0 = fmaxf(sacc[0][0], sacc[0][1]);
    float a1 = fmaxf(sacc[0][8], sacc[0][9]);
    float a2 = fmaxf(sacc[1][0], sacc[1][1]);
    float a3 = fmaxf(sacc[1][8], sacc[1][9]);
#pragma unroll
    for (int r = 2; r < 8; ++r) {
      a0 = fmaxf(a0, fmaxf(sacc[0][r], sacc[0][r + 8]));
      a2 = fmaxf(a2, fmaxf(sacc[1][r], sacc[1][r + 8]));
    }
    a1 = fmaxf(a1, a3);
    float pm = fmaxf(fmaxf(a0, a2), a1);
    pm = fmaxf(pm, __shfl_xor(pm, 32));

    if (!__all(pm - mrun <= 8.0f)) {   // defer-max (T13)
      float mnew = fmaxf(mrun, pm);
      float f = __builtin_amdgcn_exp2f(mrun - mnew);
      lrun *= f;
#pragma unroll
      for (int dt = 0; dt < 2; ++dt)
#pragma unroll
        for (int r = 0; r < 16; ++r) oacc[dt][r] *= f;
      mrun = mnew;
    }

#pragma unroll
    for (int t = 0; t < 2; ++t)
#pragma unroll
      for (int r = 0; r < 16; ++r)
        sacc[t][r] = __builtin_amdgcn_exp2f(sacc[t][r] - mrun);

    // ---- pack P to bf16: wlo/whi[t][g] = rows g*8+4*hi+{0,1}/{2,3} ----
    uint32_t wlo[2][4], whi[2][4];
#pragma unroll
    for (int t = 0; t < 2; ++t)
#pragma unroll
      for (int g = 0; g < 4; ++g) {
        wlo[t][g] = cvtpk(sacc[t][g * 4 + 0], sacc[t][g * 4 + 1]);
        whi[t][g] = cvtpk(sacc[t][g * 4 + 2], sacc[t][g * 4 + 3]);
      }

    // ---- build PV B-fragments via permlane32_swap (T12) ----
    bf16x8 pb[4];
#pragma unroll
    for (int c = 0; c < 4; ++c) {
      const int t = c >> 1, gb = (c & 1) * 2;
      uint32_t x0 = wlo[t][gb], y0 = wlo[t][gb + 1];
      p32swap(x0, y0);
      uint32_t x1 = whi[t][gb], y1 = whi[t][gb + 1];
      p32swap(x1, y1);
      u32x4 wv_;
      wv_[0] = x0; wv_[1] = x1; wv_[2] = y0; wv_[3] = y1;
      pb[c] = __builtin_bit_cast(bf16x8, wv_);
    }

    // ---- PV + row-sum via ones-MFMA ----
    f32x16 ssacc = {};
    __builtin_amdgcn_s_setprio(1);
#pragma unroll
    for (int dt = 0; dt < 2; ++dt)
#pragma unroll
      for (int c = 0; c < 4; ++c) {
        bf16x8 vfr = *(const bf16x8*)(Vb + (dt * 32 + l31) * 128 +
                                      ((c * 32 + hi * 16) ^ sw));
        oacc[dt] = mfma32(vfr, pb[c], oacc[dt]);
      }
#pragma unroll
    for (int c = 0; c < 4; ++c)
      ssacc = mfma32(ones, pb[c], ssacc);
    __builtin_amdgcn_s_setprio(0);
    lrun += ssacc[0];

    __syncthreads();   // implicit vmcnt(0): prefetch landed; all reads of cur done
    cur ^= 1;
  }

  // ---- epilogue: O[b, q, h*64 + d] = oacc^T / lrun ----
  float linv = 1.0f / lrun;
  ushort* Ob = O + (size_t)(b * 2048 + q) * 1024 + h * 64;
#pragma unroll
  for (int dt = 0; dt < 2; ++dt)
#pragma unroll
    for (int g = 0; g < 4; ++g) {
      ushort4 o4;
      o4.x = f2bf(oacc[dt][g * 4 + 0] * linv);
      o4.y = f2bf(oacc[dt][g * 4 + 1] * linv);
      o4.z = f2bf(oacc[dt][g * 4 + 2] * linv);
      o4.w = f2bf(oacc[dt][g * 4 + 3] * linv);
      *(ushort4*)(Ob + dt * 32 + g * 8 + hi * 4) = o4;
    }
}

extern "C" void kernel_launch(void* const* d_in, const int* in_sizes, int n_in,
                              void* d_out, int out_size, void* d_ws, size_t ws_size,
                              hipStream_t stream)
{
  const float* x  = (const float*)d_in[0];
  const float* Wq = (const float*)d_in[1];
  const float* bq = (const float*)d_in[2];
  const float* Wk = (const float*)d_in[3];
  const float* bk = (const float*)d_in[4];
  const float* Wv = (const float*)d_in[5];
  const float* bv = (const float*)d_in[6];
  const float* Wo = (const float*)d_in[7];
  const float* bo = (const float*)d_in[8];
  float* out = (float*)d_out;
  ushort* ws = (ushort*)d_ws;

  // workspace layout (ushort elements)
  ushort* xb   = ws;             // x bf16 [8192,1024]; later reused as attn-out
  ushort* wqkv = ws + 8388608;   // [3072,1024]
  ushort* wo   = ws + 11534336;  // [1024,1024]
  ushort* qb   = ws + 12582912;  // [B,H,S,64]
  ushort* kb   = ws + 20971520;  // [B,H,S,64]
  ushort* vb   = ws + 29360128;  // [B,H,64,S]

  cast_kernel<<<8192, 256, 0, stream>>>(x, xb);
  cast_kernel<<<1024, 256, 0, stream>>>(Wq, wqkv);
  cast_kernel<<<1024, 256, 0, stream>>>(Wk, wqkv + 1048576);
  cast_kernel<<<1024, 256, 0, stream>>>(Wv, wqkv + 2097152);
  cast_kernel<<<1024, 256, 0, stream>>>(Wo, wo);

  gemm_k<0><<<768, 512, 0, stream>>>(xb, wqkv, bq, bk, bv, qb, kb, vb, nullptr);
  attn_k<<<dim3(64, 16), 256, 0, stream>>>(qb, kb, vb, xb);
  gemm_k<1><<<256, 512, 0, stream>>>(xb, wo, bo, bo, bo, nullptr, nullptr, nullptr, out);
}